// Round 2
// baseline (450.821 us; speedup 1.0000x reference)
//
#include <hip/hip_runtime.h>
#include <hip/hip_bf16.h>

typedef __bf16 bf16;
typedef bf16 bf16x2 __attribute__((ext_vector_type(2)));
typedef bf16 bf16x8 __attribute__((ext_vector_type(8)));
typedef float f32x4 __attribute__((ext_vector_type(4)));

namespace {
constexpr int kB  = 32;    // batch
constexpr int kT  = 2048;  // seq len
constexpr int kD  = 64;    // head dim
constexpr int QB  = 64;    // q rows per block (4 waves x 16)
constexpr int KVB = 64;    // kv tile
constexpr float THR = 8.f; // defer-rescale threshold (T13)
}

// Flash-attention fwd, causal, fp32 in/out, bf16 MFMA compute.
// 4 waves/block, 16 q-rows each; KV tile 64 staged in LDS (bf16, XOR-swizzled);
// issue-early global prefetch; per-coltile causal skip; deferred rescale.
__global__ __launch_bounds__(256, 4)
void fa_fwd(const float* __restrict__ Qg, const float* __restrict__ Kg,
            const float* __restrict__ Vg, float* __restrict__ Og) {
  const int tid  = (int)threadIdx.x;
  const int wid  = tid >> 6;
  const int lane = tid & 63;
  const int g    = lane >> 4;   // 16-lane group 0..3
  const int c    = lane & 15;

  const int bid = (int)blockIdx.x;
  const int b   = bid & (kB - 1);
  const int qb  = (kT / QB - 1) - (bid >> 5);  // heavy q-blocks first
  const int q0  = qb * QB;
  const int qw  = q0 + wid * 16;               // this wave's first q row

  __shared__ __align__(16) bf16 lK[KVB * kD];      // [64 keys][64 d], swizzled
  __shared__ __align__(16) bf16 lV[kD * KVB];      // V^T: [64 d][64 keys], swizzled
  __shared__ __align__(16) bf16 lP[4][16 * KVB];   // per-wave P tile, swizzled

  const float* Qb = Qg + (size_t)b * kT * kD;
  const float* Kb = Kg + (size_t)b * kT * kD;
  const float* Vb = Vg + (size_t)b * kT * kD;
  float*       Ob = Og + (size_t)b * kT * kD;

  // ---- Q fragments, scale 1/8 folded in (exact). A-frag: row=lane&15, k=g*8+j
  bf16x8 qa[2];
#pragma unroll
  for (int kk = 0; kk < 2; ++kk) {
    const float* s = Qb + (size_t)(qw + c) * kD + kk * 32 + g * 8;
    f32x4 f0 = *(const f32x4*)(s);
    f32x4 f1 = *(const f32x4*)(s + 4);
    bf16x8 q;
#pragma unroll
    for (int j = 0; j < 4; ++j) {
      q[j]     = (bf16)(f0[j] * 0.125f);
      q[j + 4] = (bf16)(f1[j] * 0.125f);
    }
    qa[kk] = q;
  }

  f32x4 acc[4];
  float m_s[4], l_s[4];
#pragma unroll
  for (int dt = 0; dt < 4; ++dt) acc[dt] = (f32x4){0.f, 0.f, 0.f, 0.f};
#pragma unroll
  for (int r = 0; r < 4; ++r) { m_s[r] = -1e30f; l_s[r] = 0.f; }

  // staging thread->data maps
  const int krow = tid >> 2;          // 0..63
  const int kc16 = (tid & 3) << 4;    // 0,16,32,48 (16 floats per thread)
  const int vkey = (tid & 31) << 1;   // 0..62 even (2 keys per thread)
  const int vd0  = (tid >> 5) << 3;   // 0..56 (8 d per thread)

  f32x4 kp[4], vp[4];  // prefetch registers

  auto loadK = [&](int kv) {
    const float* s = Kb + (size_t)(kv + krow) * kD + kc16;
    kp[0] = ((const f32x4*)s)[0]; kp[1] = ((const f32x4*)s)[1];
    kp[2] = ((const f32x4*)s)[2]; kp[3] = ((const f32x4*)s)[3];
  };
  auto loadV = [&](int kv) {
    const float* s0 = Vb + (size_t)(kv + vkey) * kD + vd0;
    const float* s1 = s0 + kD;
    vp[0] = ((const f32x4*)s0)[0]; vp[1] = ((const f32x4*)s0)[1];
    vp[2] = ((const f32x4*)s1)[0]; vp[3] = ((const f32x4*)s1)[1];
  };
  auto stageK = [&]() {
    bf16x8 h0, h1;
#pragma unroll
    for (int j = 0; j < 4; ++j) {
      h0[j] = (bf16)kp[0][j]; h0[j + 4] = (bf16)kp[1][j];
      h1[j] = (bf16)kp[2][j]; h1[j + 4] = (bf16)kp[3][j];
    }
    *(bf16x8*)&lK[(krow * 64 + kc16)     ^ ((krow & 7) << 3)] = h0;
    *(bf16x8*)&lK[(krow * 64 + kc16 + 8) ^ ((krow & 7) << 3)] = h1;
  };
  auto stageV = [&]() {
#pragma unroll
    for (int j = 0; j < 8; ++j) {
      int d = vd0 + j;
      float a0 = (j < 4) ? vp[0][j] : vp[1][j - 4];
      float a1 = (j < 4) ? vp[2][j] : vp[3][j - 4];
      int e = (d * 64 + vkey) ^ ((d & 7) << 3);
      *(bf16x2*)&lV[e] = (bf16x2){(bf16)a0, (bf16)a1};
    }
  };

  loadK(0); loadV(0);
  const int kv_end = q0 + QB;
  for (int kv = 0; kv < kv_end; kv += KVB) {
    stageK(); stageV();          // waits on in-flight loads, converts, writes LDS
    __syncthreads();             // tile visible to all waves
    if (kv + KVB < kv_end) { loadK(kv + KVB); loadV(kv + KVB); }  // issue early

    if (kv <= qw + 15) {
      const int lim = qw + 16 - kv;                         // >= 1
      const int nct = (lim >= KVB) ? 4 : ((lim + 15) >> 4); // active 16-coltiles
      const int nkk = (nct + 1) >> 1;                       // active 32-key PV chunks
      const bool diag = (kv == q0);

      // ---- QK^T: C-layout row(q)=g*4+r, col(key)=c
      f32x4 sc[4] = {};
#pragma unroll
      for (int ct = 0; ct < 4; ++ct) {
        if (ct < nct) {
          const int rk = ct * 16 + c;
#pragma unroll
          for (int kk = 0; kk < 2; ++kk) {
            bf16x8 kf = *(const bf16x8*)&lK[(rk * 64 + kk * 32 + g * 8) ^ ((rk & 7) << 3)];
            sc[ct] = __builtin_amdgcn_mfma_f32_16x16x32_bf16(qa[kk], kf, sc[ct], 0, 0, 0);
          }
        }
      }
      // ---- causal mask (only the diagonal tile)
      if (diag) {
#pragma unroll
        for (int ct = 0; ct < 4; ++ct) {
          if (ct < nct) {
            int key = kv + ct * 16 + c;
#pragma unroll
            for (int r = 0; r < 4; ++r) {
              int row = qw + g * 4 + r;
              if (key > row) sc[ct][r] = -1e30f;
            }
          }
        }
      }
      // ---- row max + defer decision
      float mx[4];
#pragma unroll
      for (int r = 0; r < 4; ++r) {
        float v = sc[0][r];
#pragma unroll
        for (int ct = 1; ct < 4; ++ct)
          if (ct < nct) v = fmaxf(v, sc[ct][r]);
        v = fmaxf(v, __shfl_xor(v, 1, 16));
        v = fmaxf(v, __shfl_xor(v, 2, 16));
        v = fmaxf(v, __shfl_xor(v, 4, 16));
        v = fmaxf(v, __shfl_xor(v, 8, 16));
        mx[r] = v;
      }
      float need = 0.f;
#pragma unroll
      for (int r = 0; r < 4; ++r) need = fmaxf(need, mx[r] - m_s[r]);
      const bool defer = (__all(need <= THR) != 0);

      // ---- exp + row sum (+ rescale when not deferred)
#pragma unroll
      for (int r = 0; r < 4; ++r) {
        float mn;
        if (defer) {
          mn = m_s[r];
        } else {
          mn = fmaxf(m_s[r], mx[r]);
          float corr = __expf(m_s[r] - mn);
          m_s[r] = mn;
          l_s[r] *= corr;
#pragma unroll
          for (int dt = 0; dt < 4; ++dt) acc[dt][r] *= corr;
        }
        float ls = 0.f;
#pragma unroll
        for (int ct = 0; ct < 4; ++ct) {
          if (ct < nct) {
            float p = __expf(sc[ct][r] - mn);
            sc[ct][r] = p;
            ls += p;
          }
        }
        ls += __shfl_xor(ls, 1, 16);
        ls += __shfl_xor(ls, 2, 16);
        ls += __shfl_xor(ls, 4, 16);
        ls += __shfl_xor(ls, 8, 16);
        l_s[r] += ls;
      }
      // ---- P -> per-wave LDS re-layout (C-layout -> A-frag layout)
#pragma unroll
      for (int ct = 0; ct < 4; ++ct) {
        if (ct < nct) {
#pragma unroll
          for (int r = 0; r < 4; ++r) {
            int rr = g * 4 + r;
            lP[wid][(rr * 64 + ct * 16 + c) ^ ((rr & 7) << 3)] = (bf16)sc[ct][r];
          }
        } else if (ct < nkk * 2) {  // zero-fill masked coltiles inside active chunk
#pragma unroll
          for (int r = 0; r < 4; ++r) {
            int rr = g * 4 + r;
            lP[wid][(rr * 64 + ct * 16 + c) ^ ((rr & 7) << 3)] = (bf16)0.f;
          }
        }
      }
      // ---- PV
#pragma unroll
      for (int kk = 0; kk < 2; ++kk) {
        if (kk < nkk) {
          bf16x8 pf = *(const bf16x8*)&lP[wid][(c * 64 + kk * 32 + g * 8) ^ ((c & 7) << 3)];
#pragma unroll
          for (int dt = 0; dt < 4; ++dt) {
            int d = dt * 16 + c;
            bf16x8 vf = *(const bf16x8*)&lV[(d * 64 + kk * 32 + g * 8) ^ ((d & 7) << 3)];
            acc[dt] = __builtin_amdgcn_mfma_f32_16x16x32_bf16(pf, vf, acc[dt], 0, 0, 0);
          }
        }
      }
    }
    __syncthreads();
  }

  // ---- epilogue: O = acc / l
#pragma unroll
  for (int r = 0; r < 4; ++r) {
    float inv = 1.0f / l_s[r];
    int row = qw + g * 4 + r;
#pragma unroll
    for (int dt = 0; dt < 4; ++dt)
      Ob[(size_t)row * kD + dt * 16 + c] = acc[dt][r] * inv;
  }
}

extern "C" void kernel_launch(void* const* d_in, const int* in_sizes, int n_in,
                              void* d_out, int out_size, void* d_ws, size_t ws_size,
                              hipStream_t stream) {
  const float* Q = (const float*)d_in[0];
  const float* K = (const float*)d_in[1];
  const float* V = (const float*)d_in[2];
  float* O = (float*)d_out;
  dim3 grid(kB * (kT / QB));  // 1024 blocks, heavy q-blocks first
  fa_fwd<<<grid, 256, 0, stream>>>(Q, K, V, O);
}

// Round 3
// 177.497 us; speedup vs baseline: 2.5399x; 2.5399x over previous
//
#include <hip/hip_runtime.h>
#include <hip/hip_bf16.h>

typedef __bf16 bf16;
typedef bf16 bf16x2 __attribute__((ext_vector_type(2)));
typedef bf16 bf16x8 __attribute__((ext_vector_type(8)));
typedef float f32x4 __attribute__((ext_vector_type(4)));

namespace {
constexpr int kB  = 32;    // batch
constexpr int kT  = 2048;  // seq len
constexpr int kD  = 64;    // head dim
constexpr int QB  = 64;    // q rows per block (4 waves x 16)
constexpr int KVB = 64;    // kv tile
constexpr float THR = 8.f; // defer-rescale threshold (T13)
}

// Flash-attention fwd, causal, fp32 in/out, bf16 MFMA compute.
// 4 waves/block, 16 q-rows each; KV tile 64 in LDS (bf16, XOR-swizzled, 0 conflicts);
// issue-early reg prefetch (named regs, no arrays -> no scratch);
// per-coltile causal skip; deferred rescale (THR=8).
// __launch_bounds__(256,2): cap 256 VGPR — the (256,4) hint forced VGPR=64 and
// spilled 700MB to scratch (round 2 post-mortem). Do not re-add.
__global__ __launch_bounds__(256, 2)
void fa_fwd(const float* __restrict__ Qg, const float* __restrict__ Kg,
            const float* __restrict__ Vg, float* __restrict__ Og) {
  const int tid  = (int)threadIdx.x;
  const int wid  = tid >> 6;
  const int lane = tid & 63;
  const int g    = lane >> 4;   // 16-lane group 0..3
  const int c    = lane & 15;

  const int bid = (int)blockIdx.x;
  const int b   = bid & (kB - 1);
  const int qb  = (kT / QB - 1) - (bid >> 5);  // heavy q-blocks first
  const int q0  = qb * QB;
  const int qw  = q0 + wid * 16;               // this wave's first q row

  __shared__ __align__(16) bf16 lK[KVB * kD];      // [64 keys][64 d], swizzled
  __shared__ __align__(16) bf16 lV[kD * KVB];      // V^T: [64 d][64 keys], swizzled
  __shared__ __align__(16) bf16 lP[4][16 * KVB];   // per-wave P tile, swizzled

  const float* Qb = Qg + (size_t)b * kT * kD;
  const float* Kb = Kg + (size_t)b * kT * kD;
  const float* Vb = Vg + (size_t)b * kT * kD;
  float*       Ob = Og + (size_t)b * kT * kD;

  // ---- Q fragments, scale 1/8 folded in (exact). A-frag: row=lane&15, k=g*8+j
  bf16x8 qa[2];
#pragma unroll
  for (int kk = 0; kk < 2; ++kk) {
    const float* s = Qb + (size_t)(qw + c) * kD + kk * 32 + g * 8;
    f32x4 f0 = *(const f32x4*)(s);
    f32x4 f1 = *(const f32x4*)(s + 4);
    bf16x8 q;
#pragma unroll
    for (int j = 0; j < 4; ++j) {
      q[j]     = (bf16)(f0[j] * 0.125f);
      q[j + 4] = (bf16)(f1[j] * 0.125f);
    }
    qa[kk] = q;
  }

  f32x4 acc[4];
  float m_s[4], l_s[4];
#pragma unroll
  for (int dt = 0; dt < 4; ++dt) acc[dt] = (f32x4){0.f, 0.f, 0.f, 0.f};
#pragma unroll
  for (int r = 0; r < 4; ++r) { m_s[r] = -1e30f; l_s[r] = 0.f; }

  // staging thread->data maps
  const int krow = tid >> 2;          // 0..63
  const int kc16 = (tid & 3) << 4;    // 0,16,32,48 (16 floats per thread)
  const int vkey = (tid & 31) << 1;   // 0..62 even (2 keys per thread)
  const int vd0  = (tid >> 5) << 3;   // 0..56 (8 d per thread)

  // prefetch registers — individually named so nothing can go to scratch
  f32x4 kp0, kp1, kp2, kp3, vp0, vp1, vp2, vp3;

#define LOADK(KV)                                                      \
  {                                                                    \
    const float* s_ = Kb + (size_t)((KV) + krow) * kD + kc16;          \
    kp0 = ((const f32x4*)s_)[0]; kp1 = ((const f32x4*)s_)[1];          \
    kp2 = ((const f32x4*)s_)[2]; kp3 = ((const f32x4*)s_)[3];          \
  }
#define LOADV(KV)                                                      \
  {                                                                    \
    const float* s0_ = Vb + (size_t)((KV) + vkey) * kD + vd0;          \
    const float* s1_ = s0_ + kD;                                       \
    vp0 = ((const f32x4*)s0_)[0]; vp1 = ((const f32x4*)s0_)[1];        \
    vp2 = ((const f32x4*)s1_)[0]; vp3 = ((const f32x4*)s1_)[1];        \
  }
#define STAGEK()                                                       \
  {                                                                    \
    bf16x8 h0_, h1_;                                                   \
    _Pragma("unroll") for (int j = 0; j < 4; ++j) {                    \
      h0_[j] = (bf16)kp0[j]; h0_[j + 4] = (bf16)kp1[j];                \
      h1_[j] = (bf16)kp2[j]; h1_[j + 4] = (bf16)kp3[j];                \
    }                                                                  \
    *(bf16x8*)&lK[(krow * 64 + kc16)     ^ ((krow & 7) << 3)] = h0_;   \
    *(bf16x8*)&lK[(krow * 64 + kc16 + 8) ^ ((krow & 7) << 3)] = h1_;   \
  }
#define STAGEV()                                                       \
  {                                                                    \
    _Pragma("unroll") for (int j = 0; j < 8; ++j) {                    \
      int d_ = vd0 + j;                                                \
      float a0_ = (j < 4) ? vp0[j] : vp1[j - 4];                       \
      float a1_ = (j < 4) ? vp2[j] : vp3[j - 4];                       \
      int e_ = (d_ * 64 + vkey) ^ ((d_ & 7) << 3);                     \
      *(bf16x2*)&lV[e_] = (bf16x2){(bf16)a0_, (bf16)a1_};              \
    }                                                                  \
  }

  LOADK(0) LOADV(0)
  const int kv_end = q0 + QB;
  for (int kv = 0; kv < kv_end; kv += KVB) {
    STAGEK() STAGEV()            // waits on in-flight loads, converts, writes LDS
    __syncthreads();             // tile visible to all waves
    if (kv + KVB < kv_end) { LOADK(kv + KVB) LOADV(kv + KVB) }  // issue early

    if (kv <= qw + 15) {
      const int lim = qw + 16 - kv;                         // >= 1
      const int nct = (lim >= KVB) ? 4 : ((lim + 15) >> 4); // active 16-coltiles
      const int nkk = (nct + 1) >> 1;                       // active 32-key PV chunks
      const bool diag = (kv == q0);

      // ---- QK^T: C-layout row(q)=g*4+r, col(key)=c
      f32x4 sc[4] = {};
#pragma unroll
      for (int ct = 0; ct < 4; ++ct) {
        if (ct < nct) {
          const int rk = ct * 16 + c;
#pragma unroll
          for (int kk = 0; kk < 2; ++kk) {
            bf16x8 kf = *(const bf16x8*)&lK[(rk * 64 + kk * 32 + g * 8) ^ ((rk & 7) << 3)];
            sc[ct] = __builtin_amdgcn_mfma_f32_16x16x32_bf16(qa[kk], kf, sc[ct], 0, 0, 0);
          }
        }
      }
      // ---- causal mask (only the diagonal tile)
      if (diag) {
#pragma unroll
        for (int ct = 0; ct < 4; ++ct) {
          if (ct < nct) {
            int key = kv + ct * 16 + c;
#pragma unroll
            for (int r = 0; r < 4; ++r) {
              int row = qw + g * 4 + r;
              if (key > row) sc[ct][r] = -1e30f;
            }
          }
        }
      }
      // ---- row max + defer decision
      float mx[4];
#pragma unroll
      for (int r = 0; r < 4; ++r) {
        float v = sc[0][r];
#pragma unroll
        for (int ct = 1; ct < 4; ++ct)
          if (ct < nct) v = fmaxf(v, sc[ct][r]);
        v = fmaxf(v, __shfl_xor(v, 1, 16));
        v = fmaxf(v, __shfl_xor(v, 2, 16));
        v = fmaxf(v, __shfl_xor(v, 4, 16));
        v = fmaxf(v, __shfl_xor(v, 8, 16));
        mx[r] = v;
      }
      float need = 0.f;
#pragma unroll
      for (int r = 0; r < 4; ++r) need = fmaxf(need, mx[r] - m_s[r]);
      const bool defer = (__all(need <= THR) != 0);

      // ---- exp + row sum (+ rescale when not deferred)
#pragma unroll
      for (int r = 0; r < 4; ++r) {
        float mn;
        if (defer) {
          mn = m_s[r];
        } else {
          mn = fmaxf(m_s[r], mx[r]);
          float corr = __expf(m_s[r] - mn);
          m_s[r] = mn;
          l_s[r] *= corr;
#pragma unroll
          for (int dt = 0; dt < 4; ++dt) acc[dt][r] *= corr;
        }
        float ls = 0.f;
#pragma unroll
        for (int ct = 0; ct < 4; ++ct) {
          if (ct < nct) {
            float p = __expf(sc[ct][r] - mn);
            sc[ct][r] = p;
            ls += p;
          }
        }
        ls += __shfl_xor(ls, 1, 16);
        ls += __shfl_xor(ls, 2, 16);
        ls += __shfl_xor(ls, 4, 16);
        ls += __shfl_xor(ls, 8, 16);
        l_s[r] += ls;
      }
      // ---- P -> per-wave LDS re-layout (C-layout -> A-frag layout)
#pragma unroll
      for (int ct = 0; ct < 4; ++ct) {
        if (ct < nct) {
#pragma unroll
          for (int r = 0; r < 4; ++r) {
            int rr = g * 4 + r;
            lP[wid][(rr * 64 + ct * 16 + c) ^ ((rr & 7) << 3)] = (bf16)sc[ct][r];
          }
        } else if (ct < nkk * 2) {  // zero-fill masked coltiles inside active chunk
#pragma unroll
          for (int r = 0; r < 4; ++r) {
            int rr = g * 4 + r;
            lP[wid][(rr * 64 + ct * 16 + c) ^ ((rr & 7) << 3)] = (bf16)0.f;
          }
        }
      }
      // ---- PV
#pragma unroll
      for (int kk = 0; kk < 2; ++kk) {
        if (kk < nkk) {
          bf16x8 pf = *(const bf16x8*)&lP[wid][(c * 64 + kk * 32 + g * 8) ^ ((c & 7) << 3)];
#pragma unroll
          for (int dt = 0; dt < 4; ++dt) {
            int d = dt * 16 + c;
            bf16x8 vf = *(const bf16x8*)&lV[(d * 64 + kk * 32 + g * 8) ^ ((d & 7) << 3)];
            acc[dt] = __builtin_amdgcn_mfma_f32_16x16x32_bf16(pf, vf, acc[dt], 0, 0, 0);
          }
        }
      }
    }
    __syncthreads();
  }

  // ---- epilogue: O = acc / l
#pragma unroll
  for (int r = 0; r < 4; ++r) {
    float inv = 1.0f / l_s[r];
    int row = qw + g * 4 + r;
#pragma unroll
    for (int dt = 0; dt < 4; ++dt)
      Ob[(size_t)row * kD + dt * 16 + c] = acc[dt][r] * inv;
  }
}

extern "C" void kernel_launch(void* const* d_in, const int* in_sizes, int n_in,
                              void* d_out, int out_size, void* d_ws, size_t ws_size,
                              hipStream_t stream) {
  const float* Q = (const float*)d_in[0];
  const float* K = (const float*)d_in[1];
  const float* V = (const float*)d_in[2];
  float* O = (float*)d_out;
  dim3 grid(kB * (kT / QB));  // 1024 blocks, heavy q-blocks first
  fa_fwd<<<grid, 256, 0, stream>>>(Q, K, V, O);
}

// Round 5
// 129.122 us; speedup vs baseline: 3.4914x; 1.3746x over previous
//
#include <hip/hip_runtime.h>
#include <hip/hip_bf16.h>

typedef __bf16 bf16;
typedef bf16 bf16x2 __attribute__((ext_vector_type(2)));
typedef bf16 bf16x8 __attribute__((ext_vector_type(8)));
typedef float f32x2 __attribute__((ext_vector_type(2)));
typedef float f32x4 __attribute__((ext_vector_type(4)));
typedef float f32x16 __attribute__((ext_vector_type(16)));
typedef unsigned int uint;

namespace {
constexpr int kB  = 32;    // batch
constexpr int kT  = 2048;  // seq len
constexpr int kD  = 64;    // head dim
constexpr int QB  = 128;   // q rows per block (4 waves x 32)
constexpr int KVB = 64;    // kv tile
constexpr float THR = 8.f; // defer-rescale threshold (T13)
}

// Flash-attention fwd, causal, fp32 in/out, bf16 MFMA (32x32x16, swapped QK^T).
// S^T = mfma(K,Q): lane owns q=lane&31; keys split lane<->lane^32. Softmax is
// lane-local + ONE shfl_xor(32). P->PV B-frag assembled in-register via
// cvt-pack + v_permlane32_swap_b32 (T12) — no P LDS round trip.
// permlane32_swap semantics: new_vdst.hi = old_vsrc.lo; new_vsrc.lo =
// old_vdst.hi. So vdst MUST be the low-key word (round-4 bug: operands were
// reversed -> P permuted across keys -> absmax 5.3. Keep vdst=w[mb]).
// __launch_bounds__(256,2): (256,4) forced VGPR=64 -> 700MB scratch spill
// (round 2). Do not re-add.
__global__ __launch_bounds__(256, 2)
void fa_fwd(const float* __restrict__ Qg, const float* __restrict__ Kg,
            const float* __restrict__ Vg, float* __restrict__ Og) {
  const int tid  = (int)threadIdx.x;
  const int wid  = tid >> 6;
  const int lane = tid & 63;
  const int hi   = lane >> 5;    // half of wave: which k-subblock this lane feeds
  const int ql   = lane & 31;    // this lane's q row (relative), and d row for PV

  const int bid = (int)blockIdx.x;
  const int b   = bid & (kB - 1);
  const int qb  = (kT / QB - 1) - (bid >> 5);  // heavy q-blocks first
  const int q0  = qb * QB;
  const int qw  = q0 + wid * 32;               // this wave's first q row
  const int qrow = qw + ql;

  // lK/lV during main loop (16KB); reused as fp32 transpose buffer in epilogue.
  __shared__ __align__(16) char smem[4 * 32 * 36 * 4];  // 18432 B
  bf16* lK = (bf16*)smem;            // [64 keys][64 d], swizzled ^((row&7)<<3)
  bf16* lV = (bf16*)(smem + 8192);   // V^T [64 d][64 keys], swizzled ^((d&7)<<3)

  const float* Qb = Qg + ((size_t)b * kT + qw) * kD;
  const float* Kb = Kg + (size_t)b * kT * kD;
  const float* Vb = Vg + (size_t)b * kT * kD;
  float*       Ob = Og + ((size_t)b * kT + qw) * kD;

  // ---- Q fragments (B-operand of swapped QK): col=q=ql, k=hi*8+j, per 16-d block
  bf16x8 qf[4];
#pragma unroll
  for (int db = 0; db < 4; ++db) {
    const float* s = Qb + (size_t)ql * kD + db * 16 + hi * 8;
    f32x4 f0 = *(const f32x4*)s, f1 = *(const f32x4*)(s + 4);
    bf16x8 q;
#pragma unroll
    for (int j = 0; j < 4; ++j) {
      q[j]     = (bf16)(f0[j] * 0.125f);   // 1/sqrt(64) folded, exact
      q[j + 4] = (bf16)(f1[j] * 0.125f);
    }
    qf[db] = q;
  }

  f32x16 ot0 = {}, ot1 = {};   // O^T accum: d = dt*32 + (reg&3)+8*(reg>>2)+4*hi, q=ql
  float m_s = -1e30f, l_s = 0.f;

  // staging thread->data maps (same as round 3; swizzles verified 0-conflict)
  const int krow = tid >> 2;          // 0..63
  const int kc16 = (tid & 3) << 4;    // 0,16,32,48
  const int vkey = (tid & 31) << 1;   // 0..62 even
  const int vd0  = (tid >> 5) << 3;   // 0..56

  f32x4 kp0, kp1, kp2, kp3, vp0, vp1, vp2, vp3;  // named: no scratch (round-2 lesson)

#define LOADK(KV)                                                      \
  {                                                                    \
    const float* s_ = Kb + (size_t)((KV) + krow) * kD + kc16;          \
    kp0 = ((const f32x4*)s_)[0]; kp1 = ((const f32x4*)s_)[1];          \
    kp2 = ((const f32x4*)s_)[2]; kp3 = ((const f32x4*)s_)[3];          \
  }
#define LOADV(KV)                                                      \
  {                                                                    \
    const float* s0_ = Vb + (size_t)((KV) + vkey) * kD + vd0;          \
    const float* s1_ = s0_ + kD;                                       \
    vp0 = ((const f32x4*)s0_)[0]; vp1 = ((const f32x4*)s0_)[1];        \
    vp2 = ((const f32x4*)s1_)[0]; vp3 = ((const f32x4*)s1_)[1];        \
  }
#define STAGEK()                                                       \
  {                                                                    \
    bf16x8 h0_, h1_;                                                   \
    _Pragma("unroll") for (int j = 0; j < 4; ++j) {                    \
      h0_[j] = (bf16)kp0[j]; h0_[j + 4] = (bf16)kp1[j];                \
      h1_[j] = (bf16)kp2[j]; h1_[j + 4] = (bf16)kp3[j];                \
    }                                                                  \
    *(bf16x8*)&lK[(krow * 64 + kc16)     ^ ((krow & 7) << 3)] = h0_;   \
    *(bf16x8*)&lK[(krow * 64 + kc16 + 8) ^ ((krow & 7) << 3)] = h1_;   \
  }
#define STAGEV()                                                       \
  {                                                                    \
    _Pragma("unroll") for (int j = 0; j < 8; ++j) {                    \
      int d_ = vd0 + j;                                                \
      float a0_ = (j < 4) ? vp0[j] : vp1[j - 4];                       \
      float a1_ = (j < 4) ? vp2[j] : vp3[j - 4];                       \
      int e_ = (d_ * 64 + vkey) ^ ((d_ & 7) << 3);                     \
      *(bf16x2*)&lV[e_] = (bf16x2){(bf16)a0_, (bf16)a1_};              \
    }                                                                  \
  }

  LOADK(0) LOADV(0)
  const int kv_end = q0 + QB;
  for (int kv = 0; kv < kv_end; kv += KVB) {
    STAGEK() STAGEV()
    __syncthreads();
    if (kv + KVB < kv_end) { LOADK(kv + KVB) LOADV(kv + KVB) }  // issue early

    if (kv <= qw) {                       // wave-uniform causal skip
      const int nkb = (kv + 32 <= qw) ? 2 : 1;  // active 32-key subblocks

      // ---- S^T = K·Q^T : C col=q=ql, row=key_rel=(reg&3)+8*(reg>>2)+4*hi
      f32x16 st0 = {}, st1 = {};
      __builtin_amdgcn_s_setprio(1);
#pragma unroll
      for (int db = 0; db < 4; ++db) {
        bf16x8 kf = *(const bf16x8*)&lK[(ql * 64 + db * 16 + hi * 8) ^ ((ql & 7) << 3)];
        st0 = __builtin_amdgcn_mfma_f32_32x32x16_bf16(kf, qf[db], st0, 0, 0, 0);
      }
      if (nkb == 2) {
        const int r1 = 32 + ql;
#pragma unroll
        for (int db = 0; db < 4; ++db) {
          bf16x8 kf = *(const bf16x8*)&lK[(r1 * 64 + db * 16 + hi * 8) ^ ((r1 & 7) << 3)];
          st1 = __builtin_amdgcn_mfma_f32_32x32x16_bf16(kf, qf[db], st1, 0, 0, 0);
        }
      }
      __builtin_amdgcn_s_setprio(0);

      // ---- causal mask (boundary tile only)
      if (kv + (nkb << 5) > qw) {
#pragma unroll
        for (int reg = 0; reg < 16; ++reg) {
          int krel = (reg & 3) + 8 * (reg >> 2) + 4 * hi;
          if (kv + krel > qrow) st0[reg] = -1e30f;
          if (nkb == 2 && kv + 32 + krel > qrow) st1[reg] = -1e30f;
        }
      }

      // ---- online softmax: lane-local + one cross-half shfl
      float mx = -1e30f;
#pragma unroll
      for (int r = 0; r < 16; ++r) mx = fmaxf(mx, st0[r]);
      if (nkb == 2) {
#pragma unroll
        for (int r = 0; r < 16; ++r) mx = fmaxf(mx, st1[r]);
      }
      mx = fmaxf(mx, __shfl_xor(mx, 32));
      const bool defer = (__all((mx - m_s) <= THR) != 0);
      float mn = m_s;
      if (!defer) {
        mn = fmaxf(m_s, mx);
        float corr = __expf(m_s - mn);
        m_s = mn;
        l_s *= corr;
#pragma unroll
        for (int r = 0; r < 16; ++r) { ot0[r] *= corr; ot1[r] *= corr; }
      }
      float ls = 0.f;
#pragma unroll
      for (int r = 0; r < 16; ++r) { float p = __expf(st0[r] - mn); st0[r] = p; ls += p; }
      if (nkb == 2) {
#pragma unroll
        for (int r = 0; r < 16; ++r) { float p = __expf(st1[r] - mn); st1[r] = p; ls += p; }
      }
      ls += __shfl_xor(ls, 32);
      l_s += ls;

      // ---- pack P to bf16 word pairs: w[kb*8+m] = (p[2m], p[2m+1])
      uint w_[16];
#pragma unroll
      for (int m = 0; m < 8; ++m) {
        bf16x2 t = {(bf16)st0[2 * m], (bf16)st0[2 * m + 1]};
        w_[m] = __builtin_bit_cast(uint, t);
      }
      if (nkb == 2) {
#pragma unroll
        for (int m = 0; m < 8; ++m) {
          bf16x2 t = {(bf16)st1[2 * m], (bf16)st1[2 * m + 1]};
          w_[8 + m] = __builtin_bit_cast(uint, t);
        }
      }

      // ---- PV: per 16-key slice ks, assemble B-frag via 2 permlane32_swap.
      // vdst = LOW-key word (w[mb]); after swap:
      //   w[mb]   = {lo: keys(0,1),  hi: keys(8,9)}   -> frag word0
      //   w[mb+2] = {lo: keys(4,5),  hi: keys(12,13)} -> frag word2
#pragma unroll
      for (int ks = 0; ks < 4; ++ks) {
        if (ks < 2 * nkb) {
          const int mb = (ks >> 1) * 8 + (ks & 1) * 4;
          uint a0 = w_[mb], a1 = w_[mb + 1], b0 = w_[mb + 2], b1 = w_[mb + 3];
          asm volatile("v_permlane32_swap_b32 %0, %1" : "+v"(a0), "+v"(b0));
          asm volatile("v_permlane32_swap_b32 %0, %1" : "+v"(a1), "+v"(b1));
          union { uint u[4]; bf16x8 v; } pc;
          pc.u[0] = a0; pc.u[1] = a1; pc.u[2] = b0; pc.u[3] = b1;
          const bf16x8 pf = pc.v;
          __builtin_amdgcn_s_setprio(1);
          {
            bf16x8 vf0 = *(const bf16x8*)&lV[(ql * 64 + ks * 16 + hi * 8) ^ ((ql & 7) << 3)];
            ot0 = __builtin_amdgcn_mfma_f32_32x32x16_bf16(vf0, pf, ot0, 0, 0, 0);
            const int d1 = 32 + ql;
            bf16x8 vf1 = *(const bf16x8*)&lV[(d1 * 64 + ks * 16 + hi * 8) ^ ((d1 & 7) << 3)];
            ot1 = __builtin_amdgcn_mfma_f32_32x32x16_bf16(vf1, pf, ot1, 0, 0, 0);
          }
          __builtin_amdgcn_s_setprio(0);
        }
      }
    }
    __syncthreads();
  }

  // ---- epilogue: O = acc/l, via per-wave LDS transpose -> coalesced stores
  const float inv = 1.0f / l_s;
  float* ep = (float*)(void*)smem + wid * (32 * 36);  // pad 36: aligned f32x4 reads
#pragma unroll
  for (int dt = 0; dt < 2; ++dt) {
    __syncthreads();
#pragma unroll
    for (int m = 0; m < 8; ++m) {
      int d = ((2 * m) & 3) + 8 * (m >> 1) + 4 * hi;  // even -> 8B-aligned pair
      f32x2 v;
      v[0] = (dt ? ot1[2 * m]     : ot0[2 * m])     * inv;
      v[1] = (dt ? ot1[2 * m + 1] : ot0[2 * m + 1]) * inv;
      *(f32x2*)&ep[ql * 36 + d] = v;
    }
    __syncthreads();
#pragma unroll
    for (int p = 0; p < 4; ++p) {
      int q = p * 8 + (lane >> 3);
      int c = (lane & 7) * 4;
      f32x4 v = *(const f32x4*)&ep[q * 36 + c];
      *(f32x4*)&Ob[(size_t)q * kD + dt * 32 + c] = v;
    }
  }
}

extern "C" void kernel_launch(void* const* d_in, const int* in_sizes, int n_in,
                              void* d_out, int out_size, void* d_ws, size_t ws_size,
                              hipStream_t stream) {
  const float* Q = (const float*)d_in[0];
  const float* K = (const float*)d_in[1];
  const float* V = (const float*)d_in[2];
  float* O = (float*)d_out;
  dim3 grid(kB * (kT / QB));  // 512 blocks, heavy q-blocks first
  fa_fwd<<<grid, 256, 0, stream>>>(Q, K, V, O);
}